// Round 17
// baseline (815.487 us; speedup 1.0000x reference)
//
#include <hip/hip_runtime.h>
#include <stdint.h>

// ===== LinearQ4_0: out[8192,11008] = x[8192,4096] * W^T, W q4_0 packed =====
#define IN_F   4096
#define OUT_F  11008
#define M_ROWS 8192
#define BM 256
#define BN 256
#define BK 64
#define NTILE_K (IN_F / BK)   // 64 K-tiles, 2 per iteration -> 32 iters

typedef __attribute__((ext_vector_type(4))) float  f32x4;
typedef __attribute__((ext_vector_type(16))) float f32x16;
typedef __attribute__((ext_vector_type(4))) int    int4v;
typedef __attribute__((ext_vector_type(8))) unsigned short ushort8;
typedef __bf16 bf16x8 __attribute__((ext_vector_type(8)));

__device__ __forceinline__ unsigned short f2bf(float f) {
  unsigned int u = __builtin_bit_cast(unsigned int, f);
  u += 0x7fffu + ((u >> 16) & 1u);
  return (unsigned short)(u >> 16);
}

// ---- kernel 1: fused prep (R16-proven). [0,1024): W dequant; [1024,2048): x cvt. ----
__global__ __launch_bounds__(256) void prep(const int* __restrict__ w,
                                            const float* __restrict__ sc,
                                            unsigned short* __restrict__ wb,
                                            const float* __restrict__ x,
                                            unsigned short* __restrict__ xb) {
  if (blockIdx.x < 1024) {
    const int total8 = (OUT_F * IN_F) / 8;
    for (int t = blockIdx.x * 256 + threadIdx.x; t < total8; t += 1024 * 256) {
      const int f0  = t * 8;
      const int p   = f0 >> 7;
      const int nib = (f0 >> 6) & 1;
      const int j0  = f0 & 63;
      const float scale = sc[f0 >> 6];
      const int* src = w + p * 64 + j0;
      const int4v b0 = __builtin_nontemporal_load(reinterpret_cast<const int4v*>(src));
      const int4v b1 = __builtin_nontemporal_load(reinterpret_cast<const int4v*>(src + 4));
      ushort8 r;
#pragma unroll
      for (int e = 0; e < 4; ++e) {
        const int v0 = b0[e], v1 = b1[e];
        const int q0 = nib ? ((v0 << 28) >> 28) : (v0 >> 4);
        const int q1 = nib ? ((v1 << 28) >> 28) : (v1 >> 4);
        r[e]     = f2bf((float)q0 * scale);
        r[4 + e] = f2bf((float)q1 * scale);
      }
      *reinterpret_cast<ushort8*>(wb + f0) = r;
    }
  } else {
    const int total8 = (M_ROWS * IN_F) / 8;
    for (int t = (blockIdx.x - 1024) * 256 + threadIdx.x; t < total8; t += 1024 * 256) {
      const f32x4 a0 = __builtin_nontemporal_load(reinterpret_cast<const f32x4*>(x + t * 8));
      const f32x4 a1 = __builtin_nontemporal_load(reinterpret_cast<const f32x4*>(x + t * 8 + 4));
      ushort8 r;
#pragma unroll
      for (int e = 0; e < 4; ++e) {
        r[e]     = f2bf(a0[e]);
        r[4 + e] = f2bf(a1[e]);
      }
      *reinterpret_cast<ushort8*>(xb + t * 8) = r;
    }
  }
}

// ---- async global -> LDS, 16 B per lane ----
__device__ __forceinline__ void gld16(const void* g, void* l) {
  __builtin_amdgcn_global_load_lds(
      (const __attribute__((address_space(1))) unsigned int*)(uintptr_t)g,
      (__attribute__((address_space(3))) unsigned int*)(unsigned int)(uintptr_t)l,
      16, 0, 0);
}

#define BAR() do { asm volatile("" ::: "memory"); __builtin_amdgcn_s_barrier(); \
                   asm volatile("" ::: "memory"); } while (0)

// ---- kernel 2: R16 8-phase schedule, MFMA shape 32x32x16 (4x2 tiles/wave). ----
// Staging/LDS/swizzle/waits/ledger byte-identical to R16.  Per phase: read the
// NEXT phase's operands (4 A + 2 B b128, ping-pong sets); 8x mfma_32x32x16.
// Fragments: A/B lane l -> row/col l&31, k-chunk 2*s16+(l>>5) (8 contig bf16);
// swizzle key ((lane&31)>>1)&3 (mm*32 row steps don't perturb it).
// C/D (HW-verified m74/m101): col=lane&31, row=(reg&3)+8*(reg>>2)+4*(lane>>5).
__global__ __launch_bounds__(512, 2) void gemm_bt(const unsigned short* __restrict__ A,
                                                  const unsigned short* __restrict__ B,
                                                  float* __restrict__ C) {
  __shared__ __align__(16) unsigned short lds[65536];  // 128 KB

  const int NT  = OUT_F / BN;              // 43
  const int nwg = (M_ROWS / BM) * NT;      // 1376, %8==0
  const int cpx = nwg >> 3;
  const int bid = blockIdx.x;
  const int swz = (bid & 7) * cpx + (bid >> 3);
  const int mt  = swz / NT;
  const int nt  = swz - mt * NT;

  const int tid  = threadIdx.x;
  const int lane = tid & 63;
  const int wid  = tid >> 6;      // 8 waves: 2 (M) x 4 (N)
  const int wr   = wid >> 2;      // 0..1 -> 128 rows
  const int wc   = wid & 3;       // 0..3 -> 64 cols

  // ---- staging (identical to R16) ----
  const int r_st = tid >> 2;
  const int lc   = (tid & 3) ^ ((tid >> 3) & 3);
  const unsigned short* gA = A + (size_t)(mt * BM + r_st) * IN_F + lc * 8;
  const unsigned short* gB = B + (size_t)(nt * BM + r_st) * IN_F + lc * 8;
  unsigned short* ldsw = lds + tid * 8;

#define STAGE_A(b, h, kk) do {                                              \
    unsigned short* d_ = ldsw + (b) * 32768 + (h) * 8192;                   \
    const unsigned short* s_ = gA + (kk) + (h) * 32;                        \
    gld16(s_, d_); gld16(s_ + (size_t)128 * IN_F, d_ + 4096);               \
  } while (0)
#define STAGE_B(b, h, kk) do {                                              \
    unsigned short* d_ = ldsw + (b) * 32768 + 16384 + (h) * 8192;           \
    const unsigned short* s_ = gB + (kk) + (h) * 32;                        \
    gld16(s_, d_); gld16(s_ + (size_t)128 * IN_F, d_ + 4096);               \
  } while (0)

  // ---- 32x32 fragment addressing ----
  const int arow = lane & 31;             // row/col within a 32-tile
  const int kl2  = lane >> 5;             // k-half-chunk select
  const int akey = (arow >> 1) & 3;       // swizzle key (row-dependent)
  const int cs0  = ((kl2) ^ akey) * 8;    // k16 slot 0 -> chunks {0,1}
  const int cs1  = ((2 + kl2) ^ akey) * 8;// k16 slot 1 -> chunks {2,3}

  bf16x8 aS0[4], aS1[4], bS0[2], bS1[2];
#define RD_A32(dst, b, h, cs) do {                                          \
    const unsigned short* p_ = lds + (b) * 32768 + (h) * 8192               \
                             + (size_t)arow * 32 + (cs);                    \
    _Pragma("unroll") for (int mm = 0; mm < 4; ++mm)                        \
      dst[mm] = *reinterpret_cast<const bf16x8*>(                           \
          p_ + (size_t)(wr * 128 + mm * 32) * 32);                          \
  } while (0)
#define RD_B32(dst, b, h, cs) do {                                          \
    const unsigned short* p_ = lds + (b) * 32768 + 16384 + (h) * 8192       \
                             + (size_t)arow * 32 + (cs);                    \
    _Pragma("unroll") for (int nn = 0; nn < 2; ++nn)                        \
      dst[nn] = *reinterpret_cast<const bf16x8*>(                           \
          p_ + (size_t)(wc * 64 + nn * 32) * 32);                           \
  } while (0)

  f32x16 accv[4][2] = {};
#define MFMA8(aset, bset) do {                                              \
    __builtin_amdgcn_s_setprio(1);                                          \
    _Pragma("unroll") for (int mm = 0; mm < 4; ++mm)                        \
      _Pragma("unroll") for (int nn = 0; nn < 2; ++nn)                      \
        accv[mm][nn] = __builtin_amdgcn_mfma_f32_32x32x16_bf16(             \
            aset[mm], bset[nn], accv[mm][nn], 0, 0, 0);                     \
    __builtin_amdgcn_s_setprio(0);                                          \
  } while (0)

#define VWAIT6() asm volatile("s_waitcnt vmcnt(6)" ::: "memory")

  // ---- prologue (identical ledger to R16): 12 loads; vmcnt(8); pre-read P1 ops ----
  STAGE_A(0, 0, 0); STAGE_B(0, 0, 0);
  STAGE_A(0, 1, 0); STAGE_B(0, 1, 0);
  STAGE_A(1, 0, BK); STAGE_B(1, 0, BK);
  asm volatile("s_waitcnt vmcnt(8)" ::: "memory");
  BAR();
  RD_A32(aS0, 0, 0, cs0); RD_B32(bS0, 0, 0, cs0);

  for (int it = 0; it < NTILE_K / 2; ++it) {
    const int kt1 = ((2 * it + 1) & (NTILE_K - 1)) * BK;   // cur Tb
    const int kt2 = ((2 * it + 2) & (NTILE_K - 1)) * BK;   // next Ta
    const int kt3 = ((2 * it + 3) & (NTILE_K - 1)) * BK;   // next Tb

    // P1: stage 1A1 ; RD (0,kh0,s1) ; publish 0kh1 ; MFMA (0,kh0,s0)
    STAGE_A(1, 1, kt1); RD_A32(aS1, 0, 0, cs1); RD_B32(bS1, 0, 0, cs1); VWAIT6();
    BAR(); MFMA8(aS0, bS0);
    // P2: stage 1B1 ; RD (0,kh1,s0) ; MFMA (0,kh0,s1)
    STAGE_B(1, 1, kt1); RD_A32(aS0, 0, 1, cs0); RD_B32(bS0, 0, 1, cs0);
    BAR(); MFMA8(aS1, bS1);
    // P3: stage next 0A0 ; RD (0,kh1,s1) ; publish 1kh0 ; MFMA (0,kh1,s0)
    STAGE_A(0, 0, kt2); RD_A32(aS1, 0, 1, cs1); RD_B32(bS1, 0, 1, cs1); VWAIT6();
    BAR(); MFMA8(aS0, bS0);
    // P4: stage next 0B0 ; RD (1,kh0,s0) ; MFMA (0,kh1,s1)
    STAGE_B(0, 0, kt2); RD_A32(aS0, 1, 0, cs0); RD_B32(bS0, 1, 0, cs0);
    BAR(); MFMA8(aS1, bS1);
    // P5: stage next 0A1 ; RD (1,kh0,s1) ; publish 1kh1 ; MFMA (1,kh0,s0)
    STAGE_A(0, 1, kt2); RD_A32(aS1, 1, 0, cs1); RD_B32(bS1, 1, 0, cs1); VWAIT6();
    BAR(); MFMA8(aS0, bS0);
    // P6: stage next 0B1 ; RD (1,kh1,s0) ; MFMA (1,kh0,s1)
    STAGE_B(0, 1, kt2); RD_A32(aS0, 1, 1, cs0); RD_B32(bS0, 1, 1, cs0);
    BAR(); MFMA8(aS1, bS1);
    // P7: stage next 1A0 ; RD (1,kh1,s1) ; publish next 0kh0 ; MFMA (1,kh1,s0)
    STAGE_A(1, 0, kt3); RD_A32(aS1, 1, 1, cs1); RD_B32(bS1, 1, 1, cs1); VWAIT6();
    BAR(); MFMA8(aS0, bS0);
    // P8: stage next 1B0 ; RD next (0,kh0,s0) ; MFMA (1,kh1,s1)
    STAGE_B(1, 0, kt3); RD_A32(aS0, 0, 0, cs0); RD_B32(bS0, 0, 0, cs0);
    BAR(); MFMA8(aS1, bS1);
  }

  // ---- epilogue: 32x32 C/D map (m74/m101): col=lane&31, row=(r&3)+8*(r>>2)+4*(lane>>5) ----
  const int col0 = nt * BN + wc * 64 + (lane & 31);
  const int row0 = mt * BM + wr * 128 + 4 * (lane >> 5);
#pragma unroll
  for (int pm = 0; pm < 4; ++pm) {
#pragma unroll
    for (int pn = 0; pn < 2; ++pn) {
      float* cp = C + (size_t)(row0 + pm * 32) * OUT_F + (col0 + pn * 32);
#pragma unroll
      for (int r = 0; r < 16; ++r)
        cp[(size_t)((r & 3) + 8 * (r >> 2)) * OUT_F] = accv[pm][pn][r];
    }
  }
}

extern "C" void kernel_launch(void* const* d_in, const int* in_sizes, int n_in,
                              void* d_out, int out_size, void* d_ws, size_t ws_size,
                              hipStream_t stream) {
  const float* x = (const float*)d_in[0];
  const int*   w = (const int*)d_in[1];
  const float* s = (const float*)d_in[2];
  float*     out = (float*)d_out;

  unsigned short* wb = (unsigned short*)d_ws;             // bf16 W  [OUT_F][IN_F]
  unsigned short* xb = wb + (size_t)OUT_F * IN_F;         // bf16 x  [M_ROWS][IN_F]

  prep<<<dim3(2048), dim3(256), 0, stream>>>(w, s, wb, x, xb);
  gemm_bt<<<dim3((M_ROWS / BM) * (OUT_F / BN)), dim3(512), 0, stream>>>(xb, wb, out);
}

// Round 18
// 727.911 us; speedup vs baseline: 1.1203x; 1.1203x over previous
//
#include <hip/hip_runtime.h>
#include <stdint.h>

// ===== LinearQ4_0: out[8192,11008] = x[8192,4096] * W^T, W q4_0 packed =====
// FINAL (R16 configuration — session best: 737.9 us total, GEMM ~713-733 us,
// MfmaUtil 55%, SQ_LDS_BANK_CONFLICT 0).  R17's 32x32 MFMA variant regressed
// (structural 4-way LDS conflict in 64B-row layout); reverted per decision rule.
#define IN_F   4096
#define OUT_F  11008
#define M_ROWS 8192
#define BM 256
#define BN 256
#define BK 64
#define NTILE_K (IN_F / BK)   // 64 K-tiles, 2 per iteration -> 32 iters

typedef __attribute__((ext_vector_type(4))) float  f32x4;
typedef __attribute__((ext_vector_type(4))) int    int4v;
typedef __attribute__((ext_vector_type(8))) unsigned short ushort8;
typedef __bf16 bf16x8 __attribute__((ext_vector_type(8)));

__device__ __forceinline__ unsigned short f2bf(float f) {
  unsigned int u = __builtin_bit_cast(unsigned int, f);
  u += 0x7fffu + ((u >> 16) & 1u);
  return (unsigned short)(u >> 16);
}

// ---- kernel 1: fused prep. Blocks [0,1024): dequant W -> bf16; [1024,2048): x -> bf16. ----
__global__ __launch_bounds__(256) void prep(const int* __restrict__ w,
                                            const float* __restrict__ sc,
                                            unsigned short* __restrict__ wb,
                                            const float* __restrict__ x,
                                            unsigned short* __restrict__ xb) {
  if (blockIdx.x < 1024) {
    const int total8 = (OUT_F * IN_F) / 8;
    for (int t = blockIdx.x * 256 + threadIdx.x; t < total8; t += 1024 * 256) {
      const int f0  = t * 8;
      const int p   = f0 >> 7;
      const int nib = (f0 >> 6) & 1;
      const int j0  = f0 & 63;
      const float scale = sc[f0 >> 6];
      const int* src = w + p * 64 + j0;
      const int4v b0 = __builtin_nontemporal_load(reinterpret_cast<const int4v*>(src));
      const int4v b1 = __builtin_nontemporal_load(reinterpret_cast<const int4v*>(src + 4));
      ushort8 r;
#pragma unroll
      for (int e = 0; e < 4; ++e) {
        const int v0 = b0[e], v1 = b1[e];
        const int q0 = nib ? ((v0 << 28) >> 28) : (v0 >> 4);
        const int q1 = nib ? ((v1 << 28) >> 28) : (v1 >> 4);
        r[e]     = f2bf((float)q0 * scale);
        r[4 + e] = f2bf((float)q1 * scale);
      }
      *reinterpret_cast<ushort8*>(wb + f0) = r;
    }
  } else {
    const int total8 = (M_ROWS * IN_F) / 8;
    for (int t = (blockIdx.x - 1024) * 256 + threadIdx.x; t < total8; t += 1024 * 256) {
      const f32x4 a0 = __builtin_nontemporal_load(reinterpret_cast<const f32x4*>(x + t * 8));
      const f32x4 a1 = __builtin_nontemporal_load(reinterpret_cast<const f32x4*>(x + t * 8 + 4));
      ushort8 r;
#pragma unroll
      for (int e = 0; e < 4; ++e) {
        r[e]     = f2bf(a0[e]);
        r[4 + e] = f2bf(a1[e]);
      }
      *reinterpret_cast<ushort8*>(xb + t * 8) = r;
    }
  }
}

// ---- async global -> LDS, 16 B per lane ----
__device__ __forceinline__ void gld16(const void* g, void* l) {
  __builtin_amdgcn_global_load_lds(
      (const __attribute__((address_space(1))) unsigned int*)(uintptr_t)g,
      (__attribute__((address_space(3))) unsigned int*)(unsigned int)(uintptr_t)l,
      16, 0, 0);
}

#define BAR() do { asm volatile("" ::: "memory"); __builtin_amdgcn_s_barrier(); \
                   asm volatile("" ::: "memory"); } while (0)

// ---- kernel 2: 8-phase, 1 barrier/phase, ONE-PHASE-AHEAD fragment reads. ----
// Phase i = {STAGE (2 loads); RD(frags for MFMA i+1, alternate reg set);
//            [vmcnt(6) on odd phases]; BAR; MFMA(i) from current set}.
// Residency ledger (FIFO-sim; 2 loads/phase; vmcnt(6) at P1,P3,P5,P7):
//   prologue leaves [0A1,0B1,1A0,1B0] in flight (= P8-exit state).
//   P1-wait drains 0A1,0B1 (RD P2,P3)   P3-wait drains 1A0,1B0 (RD P4,P5)
//   P5-wait drains 1A1,1B1 (RD P6,P7)   P7-wait drains 0A0',0B0' (RD P8,P1')
// WAR: every stage target's last reader is a phase-top RD >=1 barrier earlier.
// LDS [buf][A|B][kh][256][32] 64B rows, swizzle chunk^=((row>>1)&3);
// linear gld dest + inverse-swizzled global source + same XOR on ds_read.
__global__ __launch_bounds__(512, 2) void gemm_bt(const unsigned short* __restrict__ A,
                                                  const unsigned short* __restrict__ B,
                                                  float* __restrict__ C) {
  __shared__ __align__(16) unsigned short lds[65536];  // 128 KB

  const int NT  = OUT_F / BN;              // 43
  const int nwg = (M_ROWS / BM) * NT;      // 1376, %8==0
  const int cpx = nwg >> 3;
  const int bid = blockIdx.x;
  const int swz = (bid & 7) * cpx + (bid >> 3);
  const int mt  = swz / NT;
  const int nt  = swz - mt * NT;

  const int tid  = threadIdx.x;
  const int lane = tid & 63;
  const int wid  = tid >> 6;      // 8 waves: 2 (M) x 4 (N)
  const int wr   = wid >> 2;      // 0..1 -> 128 rows
  const int wc   = wid & 3;       // 0..3 -> 64 cols

  // ---- staging: thread t -> row t>>2, phys chunk t&3; logical chunk = pc ^ ((row>>1)&3) ----
  const int r_st = tid >> 2;
  const int lc   = (tid & 3) ^ ((tid >> 3) & 3);
  const unsigned short* gA = A + (size_t)(mt * BM + r_st) * IN_F + lc * 8;
  const unsigned short* gB = B + (size_t)(nt * BM + r_st) * IN_F + lc * 8;
  unsigned short* ldsw = lds + tid * 8;   // linear dest within each 8KB sweep

  // region base (ushorts): buf*32768 + (B?16384:0) + kh*8192 ; sweep2 at +4096
#define STAGE_A(b, h, kk) do {                                              \
    unsigned short* d_ = ldsw + (b) * 32768 + (h) * 8192;                   \
    const unsigned short* s_ = gA + (kk) + (h) * 32;                        \
    gld16(s_, d_); gld16(s_ + (size_t)128 * IN_F, d_ + 4096);               \
  } while (0)
#define STAGE_B(b, h, kk) do {                                              \
    unsigned short* d_ = ldsw + (b) * 32768 + 16384 + (h) * 8192;           \
    const unsigned short* s_ = gB + (kk) + (h) * 32;                        \
    gld16(s_, d_); gld16(s_ + (size_t)128 * IN_F, d_ + 4096);               \
  } while (0)

  // ---- fragment reads: row (bits 0-3 = fr) -> chunk (kq ^ (fr>>1)&3) ----
  const int fr   = lane & 15;
  const int kq   = lane >> 4;
  const int coff = (kq ^ ((fr >> 1) & 3)) * 8;   // ushort offset within 32-col row

  bf16x8 aS0[4], aS1[4], bS0[4], bS1[4];
#define RD_A(dst, b, h, mq) do {                                            \
    const unsigned short* p_ = lds + (b) * 32768 + (h) * 8192 + coff;       \
    _Pragma("unroll") for (int mm = 0; mm < 4; ++mm)                        \
      dst[mm] = *reinterpret_cast<const bf16x8*>(                           \
          p_ + (size_t)(wr * 128 + (mq) * 64 + mm * 16 + fr) * 32);         \
  } while (0)
#define RD_B(dst, b, h) do {                                                \
    const unsigned short* p_ = lds + (b) * 32768 + 16384 + (h) * 8192 + coff; \
    _Pragma("unroll") for (int nn = 0; nn < 4; ++nn)                        \
      dst[nn] = *reinterpret_cast<const bf16x8*>(                           \
          p_ + (size_t)(wc * 64 + nn * 16 + fr) * 32);                      \
  } while (0)

  f32x4 acc[8][4] = {};
#define MFMA16(mq, aset, bset) do {                                         \
    __builtin_amdgcn_s_setprio(1);                                          \
    _Pragma("unroll") for (int mm = 0; mm < 4; ++mm)                        \
      _Pragma("unroll") for (int nn = 0; nn < 4; ++nn)                      \
        acc[(mq)*4+mm][nn] = __builtin_amdgcn_mfma_f32_16x16x32_bf16(       \
            aset[mm], bset[nn], acc[(mq)*4+mm][nn], 0, 0, 0);               \
    __builtin_amdgcn_s_setprio(0);                                          \
  } while (0)

#define VWAIT6() asm volatile("s_waitcnt vmcnt(6)" ::: "memory")

  // ---- prologue: 12 loads; vmcnt(8) -> 0kh0 resident; in-flight = P8-exit state;
  //      pre-read MFMA(P1)'s frags (0kh0 m0-3 + b) ----
  STAGE_A(0, 0, 0); STAGE_B(0, 0, 0);
  STAGE_A(0, 1, 0); STAGE_B(0, 1, 0);
  STAGE_A(1, 0, BK); STAGE_B(1, 0, BK);
  asm volatile("s_waitcnt vmcnt(8)" ::: "memory");
  BAR();
  RD_A(aS0, 0, 0, 0); RD_B(bS0, 0, 0);

  for (int it = 0; it < NTILE_K / 2; ++it) {
    const int kt1 = ((2 * it + 1) & (NTILE_K - 1)) * BK;   // cur Tb
    const int kt2 = ((2 * it + 2) & (NTILE_K - 1)) * BK;   // next Ta
    const int kt3 = ((2 * it + 3) & (NTILE_K - 1)) * BK;   // next Tb

    // P1: stage 1A1 ; RD->P2 (0kh0 m4-7) ; publish 0kh1 ; MFMA 0kh0 m0-3
    STAGE_A(1, 1, kt1); RD_A(aS1, 0, 0, 1); VWAIT6();
    BAR(); MFMA16(0, aS0, bS0);
    // P2: stage 1B1 ; RD->P3 (0kh1 m0-3 + b) ; MFMA 0kh0 m4-7
    STAGE_B(1, 1, kt1); RD_A(aS0, 0, 1, 0); RD_B(bS1, 0, 1);
    BAR(); MFMA16(1, aS1, bS0);
    // P3: stage next 0A0 ; RD->P4 (0kh1 m4-7) ; publish 1kh0 ; MFMA 0kh1 m0-3
    STAGE_A(0, 0, kt2); RD_A(aS1, 0, 1, 1); VWAIT6();
    BAR(); MFMA16(0, aS0, bS1);
    // P4: stage next 0B0 ; RD->P5 (1kh0 m0-3 + b) ; MFMA 0kh1 m4-7
    STAGE_B(0, 0, kt2); RD_A(aS0, 1, 0, 0); RD_B(bS0, 1, 0);
    BAR(); MFMA16(1, aS1, bS1);
    // P5: stage next 0A1 ; RD->P6 (1kh0 m4-7) ; publish 1kh1 ; MFMA 1kh0 m0-3
    STAGE_A(0, 1, kt2); RD_A(aS1, 1, 0, 1); VWAIT6();
    BAR(); MFMA16(0, aS0, bS0);
    // P6: stage next 0B1 ; RD->P7 (1kh1 m0-3 + b) ; MFMA 1kh0 m4-7
    STAGE_B(0, 1, kt2); RD_A(aS0, 1, 1, 0); RD_B(bS1, 1, 1);
    BAR(); MFMA16(1, aS1, bS0);
    // P7: stage next 1A0 ; RD->P8 (1kh1 m4-7) ; publish next 0kh0 ; MFMA 1kh1 m0-3
    STAGE_A(1, 0, kt3); RD_A(aS1, 1, 1, 1); VWAIT6();
    BAR(); MFMA16(0, aS0, bS1);
    // P8: stage next 1B0 ; RD->next P1 (next-Ta 0kh0 m0-3 + b) ; MFMA 1kh1 m4-7
    STAGE_B(1, 0, kt3); RD_A(aS0, 0, 0, 0); RD_B(bS0, 0, 0);
    BAR(); MFMA16(1, aS1, bS1);
  }

  // ---- epilogue: plain stores ----
  const int col  = nt * BN + wc * 64 + fr;
  const int row0 = mt * BM + wr * 128 + (lane >> 4) * 4;
#pragma unroll
  for (int m = 0; m < 8; ++m) {
#pragma unroll
    for (int n = 0; n < 4; ++n) {
      float* cp = C + (size_t)(row0 + m * 16) * OUT_F + (col + n * 16);
#pragma unroll
      for (int r = 0; r < 4; ++r) cp[(size_t)r * OUT_F] = acc[m][n][r];
    }
  }
}

extern "C" void kernel_launch(void* const* d_in, const int* in_sizes, int n_in,
                              void* d_out, int out_size, void* d_ws, size_t ws_size,
                              hipStream_t stream) {
  const float* x = (const float*)d_in[0];
  const int*   w = (const int*)d_in[1];
  const float* s = (const float*)d_in[2];
  float*     out = (float*)d_out;

  unsigned short* wb = (unsigned short*)d_ws;             // bf16 W  [OUT_F][IN_F]
  unsigned short* xb = wb + (size_t)OUT_F * IN_F;         // bf16 x  [M_ROWS][IN_F]

  prep<<<dim3(2048), dim3(256), 0, stream>>>(w, s, wb, x, xb);
  gemm_bt<<<dim3((M_ROWS / BM) * (OUT_F / BN)), dim3(512), 0, stream>>>(xb, wb, out);
}